// Round 14
// baseline (271.961 us; speedup 1.0000x reference)
//
#include <hip/hip_runtime.h>
#include <hip/hip_bf16.h>
#include <math.h>

// Problem constants (fixed by the reference):
// N=20000, E=320000, DIN=128, DH=64, H=8, B=16, C=10, NEG_SLOPE=0.2

#define NEG_SLOPE 0.2f

typedef float f32x2 __attribute__((ext_vector_type(2)));
typedef float f32x4 __attribute__((ext_vector_type(4)));
typedef short bf16x8 __attribute__((ext_vector_type(8)));

__device__ __forceinline__ float bf2f(__hip_bfloat16 b) { return __bfloat162float(b); }
__device__ __forceinline__ unsigned short f2bfu(float x) {
    __hip_bfloat16 b = __float2bfloat16(x);
    return *(unsigned short*)&b;
}

// fp8 e4m3 pack/unpack (OCP on gfx950)
__device__ __forceinline__ unsigned char f2fp8(float x) {
    unsigned int u = __builtin_amdgcn_cvt_pk_fp8_f32(x, x, 0, false);
    return (unsigned char)(u & 0xff);
}
__device__ __forceinline__ void unpack8_fp8(uint2 u, float* f) {
    f32x2 a = __builtin_amdgcn_cvt_pk_f32_fp8(u.x, false);
    f32x2 b = __builtin_amdgcn_cvt_pk_f32_fp8(u.x, true);
    f32x2 c = __builtin_amdgcn_cvt_pk_f32_fp8(u.y, false);
    f32x2 d = __builtin_amdgcn_cvt_pk_f32_fp8(u.y, true);
    f[0] = a[0]; f[1] = a[1]; f[2] = b[0]; f[3] = b[1];
    f[4] = c[0]; f[5] = c[1]; f[6] = d[0]; f[7] = d[1];
}

// ---------------- prep_all: W-swizzle both layers + zero cnt, hg, done-counter ------
__global__ __launch_bounds__(256) void prep_all(const float* __restrict__ W1,
                                                const float* __restrict__ W2,
                                                unsigned short* __restrict__ Bz1,
                                                unsigned short* __restrict__ Bz2,
                                                int* __restrict__ cnt,
                                                float* __restrict__ hg,
                                                int* __restrict__ done, int N) {
    int b = blockIdx.x;
    if (b < 32) {
        const float* W = (b < 16) ? W1 : W2;
        unsigned short* Wswz = (b < 16) ? Bz1 : Bz2;
        int fid = (b & 15) * 256 + threadIdx.x;     // 0..4095
        int lane = fid & 63;
        int ks = (fid >> 6) & 1;
        int ctg = fid >> 7;                          // 0..31
        int col = ctg * 16 + (lane & 15);
        int k0 = ks * 32 + ((lane >> 4) << 3);
        unsigned short v[8];
#pragma unroll
        for (int j = 0; j < 8; ++j) v[j] = f2bfu(W[(k0 + j) * 512 + col]);
        ushort4* dst = (ushort4*)(Wswz + (size_t)fid * 8);
        dst[0] = make_ushort4(v[0], v[1], v[2], v[3]);
        dst[1] = make_ushort4(v[4], v[5], v[6], v[7]);
    } else {
        for (int i = (b - 32) * 256 + threadIdx.x; i < N; i += 4 * 256) cnt[i] = 0;
        if (b == 32) {
            for (int i = threadIdx.x; i < 16 * 64; i += 256) hg[i] = 0.f;
            if (threadIdx.x == 0) *done = 0;
        }
    }
}

// ---------------- scan (exclusive prefix over cnt) ----------------
__global__ __launch_bounds__(1024) void scan_kernel(const int* __restrict__ cnt,
                                                    int* __restrict__ row_start,
                                                    int* __restrict__ cursor, int N) {
    __shared__ int part[1024];
    int t = threadIdx.x;
    int CH = (N + 1023) >> 10;
    int beg = t * CH;
    int end = beg + CH; if (end > N) end = N;
    if (beg > N) beg = N;
    int local = 0;
    for (int i = beg; i < end; ++i) local += cnt[i];
    part[t] = local;
    __syncthreads();
    for (int off = 1; off < 1024; off <<= 1) {
        int v = (t >= off) ? part[t - off] : 0;
        __syncthreads();
        part[t] += v;
        __syncthreads();
    }
    int run = part[t] - local;   // exclusive prefix
    for (int i = beg; i < end; ++i) {
        row_start[i] = run; cursor[i] = run;
        run += cnt[i];
    }
    if (t == 1023) row_start[N] = run;   // == E
}

// ---------------- FUSED: input GEMM + edge histogram ------
__global__ __launch_bounds__(256) void in_gemm_hist(const float* __restrict__ g,
                                                    const float* __restrict__ W,
                                                    const float* __restrict__ b,
                                                    float* __restrict__ h0,
                                                    const int* __restrict__ edge_dst,
                                                    int* __restrict__ cnt,
                                                    int N, int E, int nbGemm) {
    __shared__ float gt[128][36];   // gt[k][r]
    int t = threadIdx.x;
    if (blockIdx.x >= nbGemm) {
        int e = (blockIdx.x - nbGemm) * 256 + t;
        if (e < E) atomicAdd(&cnt[edge_dst[e]], 1);
        return;
    }
    int n0 = blockIdx.x * 32;
#pragma unroll
    for (int i = 0; i < 4; ++i) {
        int ch = t + i * 256;
        int r = ch >> 5, k0 = (ch & 31) << 2;
        float4 v = (n0 + r < N) ? *(const float4*)(g + (size_t)(n0 + r) * 128 + k0)
                                : make_float4(0.f, 0.f, 0.f, 0.f);
        gt[k0 + 0][r] = v.x; gt[k0 + 1][r] = v.y; gt[k0 + 2][r] = v.z; gt[k0 + 3][r] = v.w;
    }
    __syncthreads();
    int c = t & 63, rg = t >> 6;
    float acc[8];
#pragma unroll
    for (int j = 0; j < 8; ++j) acc[j] = 0.f;
#pragma unroll 4
    for (int k = 0; k < 128; ++k) {
        float w = W[k * 64 + c];
        const float* hp = &gt[k][rg * 8];
        float4 ha = *(const float4*)hp;
        float4 hb = *(const float4*)(hp + 4);
        acc[0] = fmaf(ha.x, w, acc[0]);
        acc[1] = fmaf(ha.y, w, acc[1]);
        acc[2] = fmaf(ha.z, w, acc[2]);
        acc[3] = fmaf(ha.w, w, acc[3]);
        acc[4] = fmaf(hb.x, w, acc[4]);
        acc[5] = fmaf(hb.y, w, acc[5]);
        acc[6] = fmaf(hb.z, w, acc[6]);
        acc[7] = fmaf(hb.w, w, acc[7]);
    }
    float bb = b[c];
#pragma unroll
    for (int j = 0; j < 8; ++j) {
        int r = rg * 8 + j;
        if (n0 + r < N) h0[(size_t)(n0 + r) * 64 + c] = acc[j] + bb;
    }
}

// ---------------- feat GEMM (MFMA bf16) + el/er epilogue -> fp8 feat ----------------
template <bool FUSE_SCATTER>
__global__ __launch_bounds__(512) void feat_gemm(const float* __restrict__ hin,
                                                 const unsigned short* __restrict__ Wswz,
                                                 const float* __restrict__ al,
                                                 const float* __restrict__ ar,
                                                 unsigned char* __restrict__ feat8,
                                                 __hip_bfloat16* __restrict__ el,
                                                 __hip_bfloat16* __restrict__ er,
                                                 const int* __restrict__ edge_src,
                                                 const int* __restrict__ edge_dst,
                                                 int* __restrict__ cursor,
                                                 int* __restrict__ src_sorted,
                                                 int N, int E, int nbGemm) {
    __shared__ unsigned short shA[32][72];        // bf16, padded
    __shared__ unsigned char sfp8[32][512];       // fp8 output staging
    int t = threadIdx.x;
    if (FUSE_SCATTER && blockIdx.x >= nbGemm) {
        int e = (blockIdx.x - nbGemm) * 512 + t;
        if (e < E) {
            int p = atomicAdd(&cursor[edge_dst[e]], 1);
            src_sorted[p] = edge_src[e];
        }
        return;
    }
    int n0 = blockIdx.x * 32;
    {
        int r = t >> 4, c0 = (t & 15) << 2;
        float4 v = (n0 + r < N) ? *(const float4*)(hin + (size_t)(n0 + r) * 64 + c0)
                                : make_float4(0.f, 0.f, 0.f, 0.f);
        *(ushort4*)&shA[r][c0] = make_ushort4(f2bfu(v.x), f2bfu(v.y), f2bfu(v.z), f2bfu(v.w));
    }
    __syncthreads();

    int lane = t & 63;
    int w = t >> 6;              // wave id == head
    int lr = lane & 15;
    int lg = lane >> 4;          // 0..3

    bf16x8 afrag[2][2];
#pragma unroll
    for (int rt = 0; rt < 2; ++rt)
#pragma unroll
        for (int ks = 0; ks < 2; ++ks)
            afrag[rt][ks] = *(const bf16x8*)&shA[rt * 16 + lr][ks * 32 + lg * 8];

    bf16x8 bfrag[4][2];
#pragma unroll
    for (int ct = 0; ct < 4; ++ct)
#pragma unroll
        for (int ks = 0; ks < 2; ++ks) {
            int fid = ((w * 4 + ct) * 2 + ks) * 64 + lane;
            bfrag[ct][ks] = *(const bf16x8*)(Wswz + (size_t)fid * 8);
        }

    f32x4 acc[2][4];
#pragma unroll
    for (int rt = 0; rt < 2; ++rt)
#pragma unroll
        for (int ct = 0; ct < 4; ++ct)
            acc[rt][ct] = (f32x4){0.f, 0.f, 0.f, 0.f};

#pragma unroll
    for (int rt = 0; rt < 2; ++rt)
#pragma unroll
        for (int ct = 0; ct < 4; ++ct) {
            acc[rt][ct] = __builtin_amdgcn_mfma_f32_16x16x32_bf16(afrag[rt][0], bfrag[ct][0], acc[rt][ct], 0, 0, 0);
            acc[rt][ct] = __builtin_amdgcn_mfma_f32_16x16x32_bf16(afrag[rt][1], bfrag[ct][1], acc[rt][ct], 0, 0, 0);
        }

    // ---- epilogue 1: fp8 into LDS (transpose for coalesced global store)
#pragma unroll
    for (int rt = 0; rt < 2; ++rt)
#pragma unroll
        for (int ct = 0; ct < 4; ++ct) {
            int col = w * 64 + ct * 16 + lr;
#pragma unroll
            for (int j = 0; j < 4; ++j)
                sfp8[rt * 16 + lg * 4 + j][col] = f2fp8(acc[rt][ct][j]);
        }

    // ---- epilogue 2: el/er partials (register-only)
    float alv[4], arv[4];
#pragma unroll
    for (int ct = 0; ct < 4; ++ct) {
        alv[ct] = al[w * 64 + ct * 16 + lr];
        arv[ct] = ar[w * 64 + ct * 16 + lr];
    }
    float elp[2][4], erp[2][4];
#pragma unroll
    for (int rt = 0; rt < 2; ++rt)
#pragma unroll
        for (int j = 0; j < 4; ++j) {
            float sl = 0.f, sr = 0.f;
#pragma unroll
            for (int ct = 0; ct < 4; ++ct) {
                sl = fmaf(acc[rt][ct][j], alv[ct], sl);
                sr = fmaf(acc[rt][ct][j], arv[ct], sr);
            }
            elp[rt][j] = sl; erp[rt][j] = sr;
        }
#pragma unroll
    for (int off = 1; off < 16; off <<= 1)
#pragma unroll
        for (int rt = 0; rt < 2; ++rt)
#pragma unroll
            for (int j = 0; j < 4; ++j) {
                elp[rt][j] += __shfl_xor(elp[rt][j], off, 64);
                erp[rt][j] += __shfl_xor(erp[rt][j], off, 64);
            }
    if (lr == 0) {
#pragma unroll
        for (int rt = 0; rt < 2; ++rt)
#pragma unroll
            for (int j = 0; j < 4; ++j) {
                int r = rt * 16 + lg * 4 + j;
                if (n0 + r < N) {
                    el[(size_t)(n0 + r) * 8 + w] = __float2bfloat16(elp[rt][j]);
                    er[(size_t)(n0 + r) * 8 + w] = __float2bfloat16(erp[rt][j]);
                }
            }
    }

    // ---- coalesced fp8 store
    __syncthreads();
    {
        const uint4* src = (const uint4*)&sfp8[0][0];
        uint4* dst = (uint4*)(feat8 + (size_t)n0 * 512);
        int i0 = t * 2;
        if ((size_t)n0 * 512 + (size_t)(i0 + 2) * 16 <= (size_t)N * 512) {
            dst[i0] = src[i0];
            dst[i0 + 1] = src[i0 + 1];
        }
    }
}

// ---------------- GAT aggregation: one wave per dst node, el/exp software-pipelined -------
// Per 8-edge sub-chunk: lane (h*8+e) owns THE exp for (edge e, head h). Next sub-chunk's
// el gather is issued BEFORE the current sub-chunk's feat loads+FMAs (removes the serial
// el->exp bubble). den: 1 add/lane/sub-chunk (own edge), 3-shfl reduce at end; tail kept
// in a separate all-lane accumulator. __launch_bounds__(256,8) pins VGPR<=64 (R6 lesson).
template <bool RELU>
__global__ __launch_bounds__(256, 8) void gat_aggregate(
    const unsigned char* __restrict__ feat8, const __hip_bfloat16* __restrict__ el,
    const __hip_bfloat16* __restrict__ er, const float* __restrict__ bias,
    const int* __restrict__ row_start, const int* __restrict__ src_sorted,
    float* __restrict__ hout, int N) {
    int lane = threadIdx.x & 63;
    int n = blockIdx.x * 4 + (threadIdx.x >> 6);
    if (n >= N) return;
    int h = lane >> 3;
    int le = lane & 7;
    int hb = lane & 0x38;
    float erh = bf2f(er[((unsigned)n << 3) + h]);
    int row = row_start[n];
    int deg = row_start[n + 1] - row;
    const unsigned char* featl = feat8 + lane * 8;  // per-lane base

    float acc[8];
#pragma unroll
    for (int j = 0; j < 8; ++j) acc[j] = 0.f;
    float den_p = 0.f;   // per-lane partial (own edge per sub-chunk)
    float dent = 0.f;    // tail accumulator (identical across lanes)

    for (int base = 0; base < deg; base += 64) {
        int cnt = min(deg - base, 64);
        int sv = (lane < cnt) ? src_sorted[row + base + lane] : 0;
        int nsub = cnt & ~7;

        float am_cur = 0.f;
        if (nsub > 0) {
            int se = __shfl(sv, le, 64);
            float v = bf2f(el[((unsigned)se << 3) + h]) + erh;
            v = fmaxf(v, NEG_SLOPE * v);
            am_cur = __expf(v);
        }
        for (int i0 = 0; i0 < nsub; i0 += 8) {
            bool pf = (i0 + 8 < nsub);          // wave-uniform
            float elnext = 0.f;
            if (pf) {
                int se2 = __shfl(sv, i0 + 8 + le, 64);
                elnext = bf2f(el[((unsigned)se2 << 3) + h]);   // issued early, used late
            }
            // 8 srcs + 8 loads issued before FMAs (8 in flight)
            int s0 = __shfl(sv, i0 + 0, 64), s1 = __shfl(sv, i0 + 1, 64);
            int s2 = __shfl(sv, i0 + 2, 64), s3 = __shfl(sv, i0 + 3, 64);
            int s4 = __shfl(sv, i0 + 4, 64), s5 = __shfl(sv, i0 + 5, 64);
            int s6 = __shfl(sv, i0 + 6, 64), s7 = __shfl(sv, i0 + 7, 64);
            uint2 u0 = *(const uint2*)(featl + ((unsigned)s0 << 9));
            uint2 u1 = *(const uint2*)(featl + ((unsigned)s1 << 9));
            uint2 u2 = *(const uint2*)(featl + ((unsigned)s2 << 9));
            uint2 u3 = *(const uint2*)(featl + ((unsigned)s3 << 9));
            uint2 u4 = *(const uint2*)(featl + ((unsigned)s4 << 9));
            uint2 u5 = *(const uint2*)(featl + ((unsigned)s5 << 9));
            uint2 u6 = *(const uint2*)(featl + ((unsigned)s6 << 9));
            uint2 u7 = *(const uint2*)(featl + ((unsigned)s7 << 9));
            den_p += am_cur;                     // own edge's alpha
            float f[8];
            float a;
            a = __shfl(am_cur, hb | 0, 64); unpack8_fp8(u0, f);
#pragma unroll
            for (int j = 0; j < 8; ++j) acc[j] = fmaf(a, f[j], acc[j]);
            a = __shfl(am_cur, hb | 1, 64); unpack8_fp8(u1, f);
#pragma unroll
            for (int j = 0; j < 8; ++j) acc[j] = fmaf(a, f[j], acc[j]);
            a = __shfl(am_cur, hb | 2, 64); unpack8_fp8(u2, f);
#pragma unroll
            for (int j = 0; j < 8; ++j) acc[j] = fmaf(a, f[j], acc[j]);
            a = __shfl(am_cur, hb | 3, 64); unpack8_fp8(u3, f);
#pragma unroll
            for (int j = 0; j < 8; ++j) acc[j] = fmaf(a, f[j], acc[j]);
            a = __shfl(am_cur, hb | 4, 64); unpack8_fp8(u4, f);
#pragma unroll
            for (int j = 0; j < 8; ++j) acc[j] = fmaf(a, f[j], acc[j]);
            a = __shfl(am_cur, hb | 5, 64); unpack8_fp8(u5, f);
#pragma unroll
            for (int j = 0; j < 8; ++j) acc[j] = fmaf(a, f[j], acc[j]);
            a = __shfl(am_cur, hb | 6, 64); unpack8_fp8(u6, f);
#pragma unroll
            for (int j = 0; j < 8; ++j) acc[j] = fmaf(a, f[j], acc[j]);
            a = __shfl(am_cur, hb | 7, 64); unpack8_fp8(u7, f);
#pragma unroll
            for (int j = 0; j < 8; ++j) acc[j] = fmaf(a, f[j], acc[j]);
            if (pf) {
                float v = elnext + erh;
                v = fmaxf(v, NEG_SLOPE * v);
                am_cur = __expf(v);
            }
        }
        // tail (<8 edges): all lanes compute the same alpha -> separate accumulator
        for (int i = nsub; i < cnt; ++i) {
            int s = __shfl(sv, i, 64);
            uint2 u = *(const uint2*)(featl + ((unsigned)s << 9));
            float v = bf2f(el[((unsigned)s << 3) + h]) + erh;
            v = fmaxf(v, NEG_SLOPE * v);
            float a = __expf(v);
            dent += a;
            float f[8];
            unpack8_fp8(u, f);
#pragma unroll
            for (int j = 0; j < 8; ++j) acc[j] = fmaf(a, f[j], acc[j]);
        }
    }

    // den: reduce per-lane partials across the 8 lanes of this head-group, add tail
    float den = den_p;
#pragma unroll
    for (int off = 1; off < 8; off <<= 1) den += __shfl_xor(den, off, 64);
    den += dent;

    float invd = deg > 0 ? 1.f / den : 0.f;
    const float4* bp = (const float4*)(bias + lane * 8);
    float4 b0 = bp[0], b1 = bp[1];
    float o[8];
    o[0] = fmaf(acc[0], invd, b0.x); o[1] = fmaf(acc[1], invd, b0.y);
    o[2] = fmaf(acc[2], invd, b0.z); o[3] = fmaf(acc[3], invd, b0.w);
    o[4] = fmaf(acc[4], invd, b1.x); o[5] = fmaf(acc[5], invd, b1.y);
    o[6] = fmaf(acc[6], invd, b1.z); o[7] = fmaf(acc[7], invd, b1.w);

    // head-mean: sum across lanes differing in head bits (3,4,5)
#pragma unroll
    for (int off = 8; off < 64; off <<= 1)
#pragma unroll
        for (int j = 0; j < 8; ++j)
            o[j] += __shfl_xor(o[j], off, 64);

    if (lane < 8) {
#pragma unroll
        for (int j = 0; j < 8; ++j) {
            o[j] *= 0.125f;
            if (RELU) o[j] = fmaxf(o[j], 0.f);
        }
        float4* op = (float4*)(hout + (size_t)n * 64 + lane * 8);
        op[0] = make_float4(o[0], o[1], o[2], o[3]);
        op[1] = make_float4(o[4], o[5], o[6], o[7]);
    }
}

// ---------------- readout + head fused: partial sums, last block does the head ------------
__global__ __launch_bounds__(256) void readout_head(const float* __restrict__ h2,
                                                    const int* __restrict__ gid,
                                                    const float* __restrict__ W_head,
                                                    const float* __restrict__ b_head,
                                                    float* __restrict__ hg,
                                                    int* __restrict__ done,
                                                    float* __restrict__ out, int N) {
    int t = threadIdx.x;
    int c = t & 63;
    int r = t >> 6;
    int n0 = blockIdx.x * 256;
    float sum = 0.f; int cur = -1;
    int nend = n0 + 256; if (nend > N) nend = N;
    for (int n = n0 + r; n < nend; n += 4) {
        int g = gid[n];
        if (g != cur) {
            if (cur >= 0) atomicAdd(&hg[cur * 64 + c], sum);
            cur = g; sum = 0.f;
        }
        sum += h2[(size_t)n * 64 + c];
    }
    if (cur >= 0) atomicAdd(&hg[cur * 64 + c], sum);

    // last-block-done: run the head math
    __threadfence();
    __shared__ int amLast;
    if (t == 0) amLast = (atomicAdd(done, 1) == (int)gridDim.x - 1) ? 1 : 0;
    __syncthreads();
    if (!amLast) return;

    __shared__ int scnt[17];
    __shared__ float shg[16 * 64];
    __shared__ float slog[16 * 10];
    if (t < 17) {
        int lo = 0, hi = N;   // first index with gid >= t (gids sorted)
        while (lo < hi) { int m = (lo + hi) >> 1; if (gid[m] < t) lo = m + 1; else hi = m; }
        scnt[t] = lo;
    }
    __syncthreads();
    if (t < 16) scnt[t] = scnt[t + 1] - scnt[t];
    __syncthreads();
    for (int i = t; i < 1024; i += 256) {
        int g = i >> 6;
        float v = __hip_atomic_load(&hg[i], __ATOMIC_RELAXED, __HIP_MEMORY_SCOPE_AGENT);
        shg[i] = v / fmaxf((float)scnt[g], 1.f);
    }
    __syncthreads();
    if (t < 160) {
        int g = t / 10, cc = t % 10;
        float acc = b_head[cc];
#pragma unroll 16
        for (int k = 0; k < 64; ++k) acc = fmaf(shg[g * 64 + k], W_head[k * 10 + cc], acc);
        slog[g * 10 + cc] = acc;
    }
    __syncthreads();
    if (t < 16) {
        float mx = -INFINITY;
#pragma unroll
        for (int cc = 0; cc < 10; ++cc) mx = fmaxf(mx, slog[t * 10 + cc]);
        float e[10], s = 0.f;
#pragma unroll
        for (int cc = 0; cc < 10; ++cc) { e[cc] = __expf(slog[t * 10 + cc] - mx); s += e[cc]; }
        float inv = 1.f / s;
#pragma unroll
        for (int cc = 0; cc < 10; ++cc) out[t * 10 + cc] = e[cc] * inv;
    }
}

extern "C" void kernel_launch(void* const* d_in, const int* in_sizes, int n_in,
                              void* d_out, int out_size, void* d_ws, size_t ws_size,
                              hipStream_t stream) {
    const float* g_feats  = (const float*)d_in[0];
    const int*   edge_src = (const int*)d_in[1];
    const int*   edge_dst = (const int*)d_in[2];
    const int*   gids     = (const int*)d_in[3];
    const float* W_in     = (const float*)d_in[4];
    const float* b_in     = (const float*)d_in[5];
    const float* W1       = (const float*)d_in[6];
    const float* attn_l1  = (const float*)d_in[7];
    const float* attn_r1  = (const float*)d_in[8];
    const float* bias1    = (const float*)d_in[9];
    const float* W2       = (const float*)d_in[10];
    const float* attn_l2  = (const float*)d_in[11];
    const float* attn_r2  = (const float*)d_in[12];
    const float* bias2    = (const float*)d_in[13];
    const float* W_head   = (const float*)d_in[14];
    const float* b_head   = (const float*)d_in[15];
    float* out = (float*)d_out;

    const int N = in_sizes[3];
    const int E = in_sizes[1];

    // workspace layout (16B-aligned sections)
    unsigned char* feat8 = (unsigned char*)d_ws;            // N*512 bytes (fp8)
    float* h0 = (float*)(feat8 + (size_t)N * 512);          // N*64 f32
    float* h1 = h0 + (size_t)N * 64;                        // N*64
    float* h2 = h1 + (size_t)N * 64;                        // N*64
    float* hg = h2 + (size_t)N * 64;                        // 16*64
    __hip_bfloat16* el = (__hip_bfloat16*)(hg + 16 * 64);   // N*8 bf16
    __hip_bfloat16* er = el + (size_t)N * 8;                // N*8 bf16
    unsigned short* Wz1 = (unsigned short*)(er + (size_t)N * 8);  // 32768 bf16
    unsigned short* Wz2 = Wz1 + 32768;                      // 32768 bf16
    int* cnt        = (int*)(Wz2 + 32768);                  // N
    int* row_start  = cnt + N;                              // N+1
    int* cursor     = row_start + N + 1;                    // N
    int* src_sorted = cursor + N;                           // E
    int* done       = src_sorted + E;                       // 1

    int nb4 = (N + 3) / 4;
    int nb32 = (N + 31) / 32;
    int nb256 = (N + 255) / 256;
    int eb256 = (E + 255) / 256;
    int eb512 = (E + 511) / 512;

    prep_all<<<36, 256, 0, stream>>>(W1, W2, Wz1, Wz2, cnt, hg, done, N);
    in_gemm_hist<<<nb32 + eb256, 256, 0, stream>>>(g_feats, W_in, b_in, h0,
                                                   edge_dst, cnt, N, E, nb32);
    scan_kernel<<<1, 1024, 0, stream>>>(cnt, row_start, cursor, N);
    feat_gemm<true><<<nb32 + eb512, 512, 0, stream>>>(h0, Wz1, attn_l1, attn_r1,
                                                      feat8, el, er,
                                                      edge_src, edge_dst, cursor, src_sorted,
                                                      N, E, nb32);
    gat_aggregate<true><<<nb4, 256, 0, stream>>>(feat8, el, er, bias1, row_start, src_sorted, h1, N);

    feat_gemm<false><<<nb32, 512, 0, stream>>>(h1, Wz2, attn_l2, attn_r2,
                                               feat8, el, er,
                                               nullptr, nullptr, nullptr, nullptr,
                                               N, E, nb32);
    gat_aggregate<false><<<nb4, 256, 0, stream>>>(feat8, el, er, bias2, row_start, src_sorted, h2, N);

    readout_head<<<nb256, 256, 0, stream>>>(h2, gids, W_head, b_head, hg, done, out, N);
}